// Round 2
// baseline (708.091 us; speedup 1.0000x reference)
//
#include <hip/hip_runtime.h>
#include <hip/hip_bf16.h>

#define H 512
#define W 512
#define C 32
#define O 32

using bf16x8 = __attribute__((ext_vector_type(8))) short;
using f32x4  = __attribute__((ext_vector_type(4))) float;

__device__ __forceinline__ unsigned short f2bf(float f) {
    union { float f; unsigned u; } c; c.f = f;
    unsigned r = c.u + 0x7fffu + ((c.u >> 16) & 1u);
    return (unsigned short)(r >> 16);
}

// ---------------- weight reconstruction (unchanged, verified) --------------
__global__ void recon_w(const float* __restrict__ k0, const float* __restrict__ k1,
                        const float* __restrict__ k2, const float* __restrict__ k3,
                        unsigned short* __restrict__ wout) {
    int idx = blockIdx.x * 256 + threadIdx.x;
    if (idx >= 9 * 32 * 32) return;
    int ci = idx & 31;
    int o  = (idx >> 5) & 31;
    int s  = idx >> 10;
    int i = o >> 4, j = (o >> 2) & 3, k = o & 3;
    int a = ci >> 4, b = (ci >> 2) & 3, c = ci & 3;
    float acc = 0.f;
    #pragma unroll
    for (int r = 0; r < 8; ++r)
        acc += k0[(i*2 + a)*8 + r] * k1[(j*4 + b)*8 + r]
             * k2[(k*4 + c)*8 + r] * k3[s*8 + r];
    wout[idx] = f2bf(acc);
}

// ---------------- prepass: NCHW f32 -> NHWC bf16 ---------------------------
// Lane = (px, ciq): gathers 8 plane-strided floats (each load instr is
// 4 groups of 64B-contiguous lanes), packs one 16B chunk, writes 1KB/wave
// fully coalesced. All 32 loads per thread independent -> high MLP, no LDS.
__global__ void nchw_to_nhwc(const float* __restrict__ x,
                             unsigned short* __restrict__ xb) {
    const int bid = blockIdx.x;
    const int xs = bid & 1;
    const int y  = (bid >> 1) & 511;
    const int n  = bid >> 10;
    const int tid = threadIdx.x;
    const int cq = tid & 3;
    const int pl = tid >> 2;                 // 0..63
    const int plane = H * W;
    const float* src0 = x + (size_t)(n*C + cq*8) * plane + (size_t)y * W + xs * 256;
    unsigned short* dst0 = xb + (((size_t)(n*H + y)) * W + xs * 256) * C + cq * 8;
    #pragma unroll
    for (int it = 0; it < 4; ++it) {
        int px = it * 64 + pl;
        float v[8];
        #pragma unroll
        for (int j = 0; j < 8; ++j) v[j] = src0[(size_t)j * plane + px];
        uint4 pk;
        pk.x = (unsigned)f2bf(v[0]) | ((unsigned)f2bf(v[1]) << 16);
        pk.y = (unsigned)f2bf(v[2]) | ((unsigned)f2bf(v[3]) << 16);
        pk.z = (unsigned)f2bf(v[4]) | ((unsigned)f2bf(v[5]) << 16);
        pk.w = (unsigned)f2bf(v[6]) | ((unsigned)f2bf(v[7]) << 16);
        *(uint4*)(dst0 + (size_t)px * C) = pk;
    }
}

// ---------------- conv: LDS-free L1-streaming implicit GEMM ----------------
// A-frag (m=16 px, k=32 ci) = one coalesced 16B/lane load from NHWC bf16.
// 9 taps * 2 o-halves of MFMA per m-tile; B-frags resident in 72 VGPRs.
template<bool CHECK>
__device__ __forceinline__ void do_mt(const unsigned short* __restrict__ nbase,
                                      const int* rowoff, const int* syok,
                                      int gx0, int pix, int quad,
                                      const bf16x8 (&bw)[9][2],
                                      float b0, float b1,
                                      float* __restrict__ out, int orow0, int orow1) {
    f32x4 acc0 = {b0, b0, b0, b0};
    f32x4 acc1 = {b1, b1, b1, b1};
    #pragma unroll
    for (int dy = 0; dy < 3; ++dy) {
        if (__builtin_amdgcn_readfirstlane(syok[dy])) {   // wave-uniform branch
            const unsigned short* rp = nbase + rowoff[dy] + quad * 8;
            #pragma unroll
            for (int dx = 0; dx < 3; ++dx) {
                int gx = gx0 + dx - 1 + pix;
                bf16x8 a;
                if (CHECK) {
                    bf16x8 z = {0,0,0,0,0,0,0,0};
                    a = ((unsigned)gx < (unsigned)W) ? *(const bf16x8*)(rp + gx*C) : z;
                } else {
                    a = *(const bf16x8*)(rp + gx*C);
                }
                acc0 = __builtin_amdgcn_mfma_f32_16x16x32_bf16(a, bw[dy*3+dx][0], acc0, 0, 0, 0);
                acc1 = __builtin_amdgcn_mfma_f32_16x16x32_bf16(a, bw[dy*3+dx][1], acc1, 0, 0, 0);
            }
        }
    }
    const int ob = gx0 + quad * 4;
    *(f32x4*)(out + orow0 + ob) = acc0;   // D: m = quad*4+reg (px), n = pix (o)
    *(f32x4*)(out + orow1 + ob) = acc1;
}

__launch_bounds__(256, 4)
__global__ void conv_l1(const unsigned short* __restrict__ xb,
                        const unsigned short* __restrict__ wq,
                        const float* __restrict__ bias,
                        float* __restrict__ out) {
    const int tid = threadIdx.x;
    const int bid = blockIdx.x;
    const int xh = bid & 1;            // 256-px half
    const int yg = (bid >> 1) & 63;    // 8-row group
    const int n  = bid >> 7;
    const int wave = tid >> 6;
    const int lane = tid & 63;
    const int pix = lane & 15, quad = lane >> 4;

    bf16x8 bw[9][2];                   // B[k=quad*8+j][n=o=h*16+pix]
    #pragma unroll
    for (int s = 0; s < 9; ++s)
        #pragma unroll
        for (int h = 0; h < 2; ++h)
            bw[s][h] = *(const bf16x8*)(wq + ((s*32 + h*16 + pix)*32 + quad*8));

    const float b0 = bias[pix];
    const float b1 = bias[16 + pix];
    const unsigned short* nbase = xb + (size_t)n * (H * W * C);
    const int xbase = xh * 256;

    for (int rr = 0; rr < 2; ++rr) {
        const int gy = yg * 8 + wave * 2 + rr;
        int rowoff[3], syok[3];
        #pragma unroll
        for (int dy = 0; dy < 3; ++dy) {
            int sy = gy + dy - 1;
            syok[dy] = ((unsigned)sy < (unsigned)H) ? 1 : 0;
            rowoff[dy] = (syok[dy] ? sy : 0) * (W * C);
        }
        const int orow0 = ((n*O + pix) * H + gy) * W;
        const int orow1 = orow0 + 16 * H * W;

        do_mt<true >(nbase, rowoff, syok, xbase + 0,   pix, quad, bw, b0, b1, out, orow0, orow1);
        #pragma unroll 2
        for (int xm = 16; xm < 240; xm += 16)
            do_mt<false>(nbase, rowoff, syok, xbase + xm, pix, quad, bw, b0, b1, out, orow0, orow1);
        do_mt<true >(nbase, rowoff, syok, xbase + 240, pix, quad, bw, b0, b1, out, orow0, orow1);
    }
}

// ---------------- round-1 fallback (used only if ws too small) -------------
#define TW 64
#define TH 8
__launch_bounds__(256, 2)
__global__ void conv_mfma(const float* __restrict__ x,
                          const unsigned short* __restrict__ wq,
                          const float* __restrict__ bias,
                          float* __restrict__ out) {
    __shared__ __align__(16) unsigned short sx[TH + 2][TW + 2][C];
    const int tid = threadIdx.x;
    const int bid = blockIdx.x;
    const int n  = bid >> 9;
    const int r2 = bid & 511;
    const int ty = r2 >> 3;
    const int tx = r2 & 7;
    const int y0 = ty * TH, x0 = tx * TW;
    const int lane = tid & 63;
    const int pix  = lane & 15;
    const int quad = lane >> 4;
    bf16x8 bw[9][2];
    #pragma unroll
    for (int s = 0; s < 9; ++s)
        #pragma unroll
        for (int h = 0; h < 2; ++h)
            bw[s][h] = *(const bf16x8*)(wq + ((s*32 + h*16 + pix)*32 + quad*8));
    for (int task = tid; task < (TH + 2) * 4 * (TW + 2); task += 256) {
        int gxl = task % (TW + 2);
        int t2  = task / (TW + 2);
        int ciq = t2 & 3;
        int row = t2 >> 2;
        int gy = y0 + row - 1;
        int gx = x0 + gxl - 1;
        bool inb = (gy >= 0) && (gy < H) && (gx >= 0) && (gx < W);
        const float* p = x + (((n*C + ciq*8)*H + gy)*W + gx);
        float v[8];
        #pragma unroll
        for (int j2 = 0; j2 < 8; ++j2) v[j2] = inb ? p[j2 * H * W] : 0.f;
        uint4 pk;
        pk.x = (unsigned)f2bf(v[0]) | ((unsigned)f2bf(v[1]) << 16);
        pk.y = (unsigned)f2bf(v[2]) | ((unsigned)f2bf(v[3]) << 16);
        pk.z = (unsigned)f2bf(v[4]) | ((unsigned)f2bf(v[5]) << 16);
        pk.w = (unsigned)f2bf(v[6]) | ((unsigned)f2bf(v[7]) << 16);
        *(uint4*)&sx[row][gxl][ciq * 8] = pk;
    }
    __syncthreads();
    const int wave = tid >> 6;
    const float b0 = bias[pix];
    const float b1 = bias[16 + pix];
    for (int mt = 0; mt < 8; ++mt) {
        const int rr = mt >> 2;
        const int xm = (mt & 3) << 4;
        const int wrow = wave * 2 + rr;
        f32x4 acc0 = {0.f, 0.f, 0.f, 0.f};
        f32x4 acc1 = {0.f, 0.f, 0.f, 0.f};
        #pragma unroll
        for (int s = 0; s < 9; ++s) {
            const int dy = s / 3, dx = s % 3;
            bf16x8 a = *(const bf16x8*)&sx[wrow + dy][xm + pix + dx][quad * 8];
            acc0 = __builtin_amdgcn_mfma_f32_16x16x32_bf16(a, bw[s][0], acc0, 0, 0, 0);
            acc1 = __builtin_amdgcn_mfma_f32_16x16x32_bf16(a, bw[s][1], acc1, 0, 0, 0);
        }
        const int gy = y0 + wrow;
        const int base0 = ((n*O + pix)      * H + gy) * W + x0 + xm + quad * 4;
        const int base1 = ((n*O + 16 + pix) * H + gy) * W + x0 + xm + quad * 4;
        #pragma unroll
        for (int t = 0; t < 4; ++t) {
            out[base0 + t] = acc0[t] + b0;
            out[base1 + t] = acc1[t] + b1;
        }
    }
}

extern "C" void kernel_launch(void* const* d_in, const int* in_sizes, int n_in,
                              void* d_out, int out_size, void* d_ws, size_t ws_size,
                              hipStream_t stream) {
    const float* x    = (const float*)d_in[0];
    const float* k0   = (const float*)d_in[1];
    const float* k1   = (const float*)d_in[2];
    const float* k2   = (const float*)d_in[3];
    const float* k3   = (const float*)d_in[4];
    const float* bias = (const float*)d_in[5];
    float* out = (float*)d_out;

    unsigned short* wq = (unsigned short*)d_ws;          // 18 KB
    recon_w<<<36, 256, 0, stream>>>(k0, k1, k2, k3, wq);

    const size_t xb_off  = 32768;
    const size_t xb_size = (size_t)8 * H * W * C * 2;    // 134 MB NHWC bf16
    if (ws_size >= xb_off + xb_size) {
        unsigned short* xb = (unsigned short*)((char*)d_ws + xb_off);
        nchw_to_nhwc<<<8 * H * 2 / 1, 256, 0, stream>>>(x, xb);  // 8192 blocks
        conv_l1<<<8 * 64 * 2, 256, 0, stream>>>(xb, wq, bias, out);  // 1024 blocks
    } else {
        conv_mfma<<<4096, 256, 0, stream>>>(x, wq, bias, out);   // fallback
    }
}